// Round 1
// baseline (440.291 us; speedup 1.0000x reference)
//
#include <hip/hip_runtime.h>

#define Bsz 8
#define Tn  2048
#define Cn  1024
#define Hn  16
#define Sn  64
#define Mn  (Bsz * Tn)   // 16384
#define NC  32
#define LCH (Tn / NC)    // 64

typedef __attribute__((ext_vector_type(8))) short bf16x8;
typedef __attribute__((ext_vector_type(4))) float f32x4;

__device__ __forceinline__ unsigned short f2bf(float f) {
  union { float f; unsigned int u; } v;
  v.f = f;
  unsigned int r = (v.u + 0x7FFFu + ((v.u >> 16) & 1u)) >> 16;
  return (unsigned short)r;
}

// ---------------- weight fp32 -> bf16 ----------------
__global__ void wconv_kernel(const float* __restrict__ Wk, const float* __restrict__ Wv,
                             const float* __restrict__ Wr, const float* __restrict__ Wo,
                             unsigned short* __restrict__ out) {
  int i = blockIdx.x * blockDim.x + threadIdx.x;  // one group of 4 elems
  int which = i >> 18;                            // 2^18 groups per 1M-elem matrix
  int off = (i & 0x3FFFF) * 4;
  const float* src = which == 0 ? Wk : which == 1 ? Wv : which == 2 ? Wr : Wo;
  float4 f = *(const float4*)(src + off);
  ushort4 o;
  o.x = f2bf(f.x); o.y = f2bf(f.y); o.z = f2bf(f.z); o.w = f2bf(f.w);
  *(ushort4*)(out + (size_t)which * (Cn * Cn) + off) = o;
}

// ---------------- time-shift mix: out = xx + tm*(x - xx), bf16 ----------------
__global__ void mix_kernel(const float* __restrict__ x, const float* __restrict__ tm,
                           unsigned short* __restrict__ out) {
  int idx = blockIdx.x * blockDim.x + threadIdx.x;  // group of 4 elems
  int c4 = idx & (Cn / 4 - 1);
  int bt = idx >> 8;          // Cn/4 = 256
  int t = bt & (Tn - 1);
  size_t base = (size_t)bt * Cn + c4 * 4;
  float4 xv = *(const float4*)(x + base);
  float4 xxv = {0.f, 0.f, 0.f, 0.f};
  if (t != 0) xxv = *(const float4*)(x + base - Cn);
  float4 tmv = *(const float4*)(tm + c4 * 4);
  ushort4 o;
  o.x = f2bf(xxv.x + tmv.x * (xv.x - xxv.x));
  o.y = f2bf(xxv.y + tmv.y * (xv.y - xxv.y));
  o.z = f2bf(xxv.z + tmv.z * (xv.z - xxv.z));
  o.w = f2bf(xxv.w + tmv.w * (xv.w - xxv.w));
  *(ushort4*)(out + base) = o;
}

// ---------------- bf16 GEMM: C[m,n] = sum_k A[m,k] * Bt[n,k] (m97 structure) ----------------
#define BM 128
#define BN 128
#define BK 32

__device__ __forceinline__ void gload_lds16(const void* g, void* l) {
  __builtin_amdgcn_global_load_lds((const __attribute__((address_space(1))) void*)g,
                                   (__attribute__((address_space(3))) void*)l, 16, 0, 0);
}

__global__ __launch_bounds__(256) void gemm_bt(const unsigned short* __restrict__ A,
                                               const unsigned short* __restrict__ Bt,
                                               float* __restrict__ Cm,
                                               int Mdim, int Ndim, int Kdim) {
  __shared__ unsigned short As[BM * BK];
  __shared__ unsigned short Bs[BN * BK];
  const int NT = Ndim / BN;
  const int mt = blockIdx.x / NT;
  const int nt = blockIdx.x % NT;
  const int m0 = mt * BM, n0 = nt * BN;
  const int tid = threadIdx.x;
  const int wave = tid >> 6, lane = tid & 63;
  const int wm = wave >> 1, wn = wave & 1;

  f32x4 acc[4][4] = {};

  const int srow = lane >> 2;        // row within 16-row segment
  const int skoff = (lane & 3) * 8;  // k-element offset within BK

  const unsigned short* Ag0 = A + (size_t)m0 * Kdim;
  const unsigned short* Bg0 = Bt + (size_t)n0 * Kdim;

  const int frow = lane & 15;
  const int fk = (lane >> 4) * 8;

  for (int k0 = 0; k0 < Kdim; k0 += BK) {
#pragma unroll
    for (int i = 0; i < 2; ++i) {
      int seg = wave + i * 4;  // 0..7, wave-uniform
      int row = seg * 16 + srow;
      const unsigned short* ga = Ag0 + (size_t)row * Kdim + k0 + skoff;
      const unsigned short* gb = Bg0 + (size_t)row * Kdim + k0 + skoff;
      gload_lds16(ga, &As[seg * 512]);
      gload_lds16(gb, &Bs[seg * 512]);
    }
    __syncthreads();
    bf16x8 af[4], bfr[4];
#pragma unroll
    for (int i = 0; i < 4; ++i) {
      af[i] = *(const bf16x8*)&As[(wm * 64 + i * 16 + frow) * BK + fk];
      bfr[i] = *(const bf16x8*)&Bs[(wn * 64 + i * 16 + frow) * BK + fk];
    }
#pragma unroll
    for (int i = 0; i < 4; ++i)
#pragma unroll
      for (int j = 0; j < 4; ++j)
        acc[i][j] = __builtin_amdgcn_mfma_f32_16x16x32_bf16(af[i], bfr[j], acc[i][j], 0, 0, 0);
    __syncthreads();
  }

  const int crow0 = (lane >> 4) * 4;
  const int ccol = lane & 15;
#pragma unroll
  for (int i = 0; i < 4; ++i)
#pragma unroll
    for (int j = 0; j < 4; ++j)
#pragma unroll
      for (int rr = 0; rr < 4; ++rr) {
        int row = m0 + wm * 64 + i * 16 + crow0 + rr;
        int col = n0 + wn * 64 + j * 16 + ccol;
        Cm[(size_t)row * Ndim + col] = acc[i][j][rr];
      }
}

// ---------------- chunked scan ----------------
// phase1: per-chunk local end state (zero init)
__global__ void scan_phase1(const float* __restrict__ k, const float* __restrict__ v,
                            const float* __restrict__ td, float* __restrict__ cs) {
  int blk = blockIdx.x;       // bh*NC + c
  int c = blk & (NC - 1);
  int bh = blk >> 5;
  int b = bh >> 4;            // H = 16
  int h = bh & 15;
  int s = threadIdx.x;
  float decay = expf(td[h * Sn + s]);
  size_t base = ((size_t)(b * Tn + c * LCH)) * Cn + h * Sn + s;
  float st = 0.f;
#pragma unroll 8
  for (int i = 0; i < LCH; ++i) {
    float kv = k[base] * v[base];
    st = kv + decay * st;
    base += Cn;
  }
  cs[(size_t)blk * Sn + s] = st;
}

// phase2: exclusive scan of chunk carries (exact decay^L via exp(td*L))
__global__ void scan_phase2(const float* __restrict__ td, float* __restrict__ cs) {
  int bh = blockIdx.x;
  int h = bh & 15;
  int s = threadIdx.x;
  float dL = expf(td[h * Sn + s] * (float)LCH);
  float carry = 0.f;
  for (int c = 0; c < NC; ++c) {
    size_t idx = ((size_t)bh * NC + c) * Sn + s;
    float sc = cs[idx];
    cs[idx] = carry;
    carry = sc + dL * carry;
  }
}

// phase3: replay chunk with carried init state, write o (in-place over k is safe)
__global__ void scan_phase3(const float* k, const float* v, const float* r,
                            const float* td, const float* tf, const float* cs,
                            float* out) {
  int blk = blockIdx.x;
  int c = blk & (NC - 1);
  int bh = blk >> 5;
  int b = bh >> 4;
  int h = bh & 15;
  int s = threadIdx.x;
  float decay = expf(td[h * Sn + s]);
  float first = tf[h * Sn + s];
  float st = cs[(size_t)blk * Sn + s];
  size_t base = ((size_t)(b * Tn + c * LCH)) * Cn + h * Sn + s;
#pragma unroll 8
  for (int i = 0; i < LCH; ++i) {
    float kv = k[base] * v[base];
    st = kv + decay * st;
    out[base] = r[base] * (first * kv + st);
    base += Cn;
  }
}

// ---------------- layernorm -> bf16 ----------------
__global__ __launch_bounds__(256) void ln_kernel(const float* __restrict__ in,
                                                 const float* __restrict__ g,
                                                 const float* __restrict__ bb,
                                                 unsigned short* __restrict__ out) {
  int row = blockIdx.x;
  int tid = threadIdx.x;
  size_t base = (size_t)row * Cn + tid * 4;
  float4 xv = *(const float4*)(in + base);
  float sum = xv.x + xv.y + xv.z + xv.w;
  float ss = xv.x * xv.x + xv.y * xv.y + xv.z * xv.z + xv.w * xv.w;
#pragma unroll
  for (int off = 32; off >= 1; off >>= 1) {
    sum += __shfl_down(sum, off, 64);
    ss += __shfl_down(ss, off, 64);
  }
  __shared__ float s1[4], s2[4];
  if ((tid & 63) == 0) { s1[tid >> 6] = sum; s2[tid >> 6] = ss; }
  __syncthreads();
  sum = s1[0] + s1[1] + s1[2] + s1[3];
  ss = s2[0] + s2[1] + s2[2] + s2[3];
  float mu = sum * (1.f / Cn);
  float var = ss * (1.f / Cn) - mu * mu;
  float rstd = rsqrtf(var + 1e-5f);
  float4 gv = *(const float4*)(g + tid * 4);
  float4 bv = *(const float4*)(bb + tid * 4);
  ushort4 o;
  o.x = f2bf((xv.x - mu) * rstd * gv.x + bv.x);
  o.y = f2bf((xv.y - mu) * rstd * gv.y + bv.y);
  o.z = f2bf((xv.z - mu) * rstd * gv.z + bv.z);
  o.w = f2bf((xv.w - mu) * rstd * gv.w + bv.w);
  *(ushort4*)(out + base) = o;
}

extern "C" void kernel_launch(void* const* d_in, const int* in_sizes, int n_in,
                              void* d_out, int out_size, void* d_ws, size_t ws_size,
                              hipStream_t stream) {
  const float* x   = (const float*)d_in[0];
  const float* tmk = (const float*)d_in[1];
  const float* tmv = (const float*)d_in[2];
  const float* tmr = (const float*)d_in[3];
  const float* td  = (const float*)d_in[4];
  const float* tf  = (const float*)d_in[5];
  const float* Wk  = (const float*)d_in[6];
  const float* Wv  = (const float*)d_in[7];
  const float* Wr  = (const float*)d_in[8];
  const float* Wo  = (const float*)d_in[9];
  const float* lng = (const float*)d_in[10];
  const float* lnb = (const float*)d_in[11];
  float* out = (float*)d_out;

  char* ws = (char*)d_ws;
  unsigned short* wbf   = (unsigned short*)(ws);                          // 8 MB
  unsigned short* xmix  = (unsigned short*)(ws + (size_t)8 * 1024 * 1024);   // 32 MB (reused as ln_out)
  float* bufK   = (float*)(ws + (size_t)40 * 1024 * 1024);                // 64 MB (reused as preLN)
  float* bufV   = (float*)(ws + (size_t)104 * 1024 * 1024);               // 64 MB
  float* bufR   = (float*)(ws + (size_t)168 * 1024 * 1024);               // 64 MB
  float* chunkS = (float*)(ws + (size_t)232 * 1024 * 1024);               // 1 MB

  const int gemm_grid = (Mn / BM) * (Cn / BN);  // 128 * 8 = 1024
  const int mix_grid = Mn * (Cn / 4) / 256;     // 16384

  wconv_kernel<<<4 * Cn * Cn / 4 / 256, 256, 0, stream>>>(Wk, Wv, Wr, Wo, wbf);

  // k projection
  mix_kernel<<<mix_grid, 256, 0, stream>>>(x, tmk, xmix);
  gemm_bt<<<gemm_grid, 256, 0, stream>>>(xmix, wbf + 0 * (size_t)Cn * Cn, bufK, Mn, Cn, Cn);
  // v projection
  mix_kernel<<<mix_grid, 256, 0, stream>>>(x, tmv, xmix);
  gemm_bt<<<gemm_grid, 256, 0, stream>>>(xmix, wbf + 1 * (size_t)Cn * Cn, bufV, Mn, Cn, Cn);
  // r projection
  mix_kernel<<<mix_grid, 256, 0, stream>>>(x, tmr, xmix);
  gemm_bt<<<gemm_grid, 256, 0, stream>>>(xmix, wbf + 2 * (size_t)Cn * Cn, bufR, Mn, Cn, Cn);

  // chunked scan
  scan_phase1<<<Bsz * Hn * NC, 64, 0, stream>>>(bufK, bufV, td, chunkS);
  scan_phase2<<<Bsz * Hn, 64, 0, stream>>>(td, chunkS);
  scan_phase3<<<Bsz * Hn * NC, 64, 0, stream>>>(bufK, bufV, bufR, td, tf, chunkS, bufK);

  // layernorm -> bf16 (into xmix)
  ln_kernel<<<Mn, 256, 0, stream>>>(bufK, lng, lnb, xmix);

  // output projection
  gemm_bt<<<gemm_grid, 256, 0, stream>>>(xmix, wbf + 3 * (size_t)Cn * Cn, out, Mn, Cn, Cn);

  (void)in_sizes; (void)n_in; (void)out_size; (void)ws_size;
}

// Round 2
// 332.866 us; speedup vs baseline: 1.3227x; 1.3227x over previous
//
#include <hip/hip_runtime.h>

#define Bsz 8
#define Tn  2048
#define Cn  1024
#define Hn  16
#define Sn  64
#define Mn  (Bsz * Tn)   // 16384
#define NC  32
#define LCH (Tn / NC)    // 64

typedef __attribute__((ext_vector_type(8))) short bf16x8;
typedef __attribute__((ext_vector_type(4))) float f32x4;

__device__ __forceinline__ unsigned short f2bf(float f) {
  union { float f; unsigned int u; } v;
  v.f = f;
  unsigned int r = (v.u + 0x7FFFu + ((v.u >> 16) & 1u)) >> 16;
  return (unsigned short)r;
}
__device__ __forceinline__ float bf2f(unsigned short u) {
  union { unsigned int u; float f; } v;
  v.u = ((unsigned int)u) << 16;
  return v.f;
}

// ---------------- weight fp32 -> bf16 ----------------
__global__ void wconv_kernel(const float* __restrict__ Wk, const float* __restrict__ Wv,
                             const float* __restrict__ Wr, const float* __restrict__ Wo,
                             unsigned short* __restrict__ out) {
  int i = blockIdx.x * blockDim.x + threadIdx.x;  // one group of 4 elems
  int which = i >> 18;
  int off = (i & 0x3FFFF) * 4;
  const float* src = which == 0 ? Wk : which == 1 ? Wv : which == 2 ? Wr : Wo;
  float4 f = *(const float4*)(src + off);
  ushort4 o;
  o.x = f2bf(f.x); o.y = f2bf(f.y); o.z = f2bf(f.z); o.w = f2bf(f.w);
  *(ushort4*)(out + (size_t)which * (Cn * Cn) + off) = o;
}

// ---------------- fused time-shift mix: three outputs in one pass ----------------
__global__ void mix3_kernel(const float* __restrict__ x,
                            const float* __restrict__ tmk, const float* __restrict__ tmv,
                            const float* __restrict__ tmr,
                            unsigned short* __restrict__ ok, unsigned short* __restrict__ ov,
                            unsigned short* __restrict__ orr) {
  int idx = blockIdx.x * blockDim.x + threadIdx.x;  // group of 4 elems
  int c4 = idx & (Cn / 4 - 1);
  int bt = idx >> 8;
  int t = bt & (Tn - 1);
  size_t base = (size_t)bt * Cn + c4 * 4;
  float4 xv = *(const float4*)(x + base);
  float4 xxv = {0.f, 0.f, 0.f, 0.f};
  if (t != 0) xxv = *(const float4*)(x + base - Cn);
  float4 dx = {xv.x - xxv.x, xv.y - xxv.y, xv.z - xxv.z, xv.w - xxv.w};

  float4 tk = *(const float4*)(tmk + c4 * 4);
  float4 tv = *(const float4*)(tmv + c4 * 4);
  float4 tr = *(const float4*)(tmr + c4 * 4);
  ushort4 a, b, c;
  a.x = f2bf(xxv.x + tk.x * dx.x); a.y = f2bf(xxv.y + tk.y * dx.y);
  a.z = f2bf(xxv.z + tk.z * dx.z); a.w = f2bf(xxv.w + tk.w * dx.w);
  b.x = f2bf(xxv.x + tv.x * dx.x); b.y = f2bf(xxv.y + tv.y * dx.y);
  b.z = f2bf(xxv.z + tv.z * dx.z); b.w = f2bf(xxv.w + tv.w * dx.w);
  c.x = f2bf(xxv.x + tr.x * dx.x); c.y = f2bf(xxv.y + tr.y * dx.y);
  c.z = f2bf(xxv.z + tr.z * dx.z); c.w = f2bf(xxv.w + tr.w * dx.w);
  *(ushort4*)(ok + base) = a;
  *(ushort4*)(ov + base) = b;
  *(ushort4*)(orr + base) = c;
}

// ---------------- bf16 GEMM: C[m,n] = sum_k A[m,k] * Bt[n,k] ----------------
#define BM 128
#define BN 128
#define BK 32

__device__ __forceinline__ void gload_lds16(const void* g, void* l) {
  __builtin_amdgcn_global_load_lds((const __attribute__((address_space(1))) void*)g,
                                   (__attribute__((address_space(3))) void*)l, 16, 0, 0);
}

template <bool OUTBF16>
__global__ __launch_bounds__(256) void gemm_bt(const unsigned short* __restrict__ A,
                                               const unsigned short* __restrict__ Bt,
                                               void* __restrict__ Cm,
                                               int Mdim, int Ndim, int Kdim) {
  __shared__ unsigned short As[BM * BK];
  __shared__ unsigned short Bs[BN * BK];
  const int NT = Ndim / BN;
  // XCD-bijective swizzle (nwg divisible by 8): XCD x gets a contiguous tile chunk
  const int nwg = gridDim.x;
  int bid = blockIdx.x;
  bid = (bid & 7) * (nwg >> 3) + (bid >> 3);
  const int mt = bid / NT;
  const int nt = bid % NT;
  const int m0 = mt * BM, n0 = nt * BN;
  const int tid = threadIdx.x;
  const int wave = tid >> 6, lane = tid & 63;
  const int wm = wave >> 1, wn = wave & 1;

  f32x4 acc[4][4] = {};

  const int srow = lane >> 2;
  const int skoff = (lane & 3) * 8;

  const unsigned short* Ag0 = A + (size_t)m0 * Kdim;
  const unsigned short* Bg0 = Bt + (size_t)n0 * Kdim;

  const int frow = lane & 15;
  const int fk = (lane >> 4) * 8;

  for (int k0 = 0; k0 < Kdim; k0 += BK) {
#pragma unroll
    for (int i = 0; i < 2; ++i) {
      int seg = wave + i * 4;
      int row = seg * 16 + srow;
      const unsigned short* ga = Ag0 + (size_t)row * Kdim + k0 + skoff;
      const unsigned short* gb = Bg0 + (size_t)row * Kdim + k0 + skoff;
      gload_lds16(ga, &As[seg * 512]);
      gload_lds16(gb, &Bs[seg * 512]);
    }
    __syncthreads();
    bf16x8 af[4], bfr[4];
#pragma unroll
    for (int i = 0; i < 4; ++i) {
      af[i] = *(const bf16x8*)&As[(wm * 64 + i * 16 + frow) * BK + fk];
      bfr[i] = *(const bf16x8*)&Bs[(wn * 64 + i * 16 + frow) * BK + fk];
    }
#pragma unroll
    for (int i = 0; i < 4; ++i)
#pragma unroll
      for (int j = 0; j < 4; ++j)
        acc[i][j] = __builtin_amdgcn_mfma_f32_16x16x32_bf16(af[i], bfr[j], acc[i][j], 0, 0, 0);
    __syncthreads();
  }

  const int crow0 = (lane >> 4) * 4;
  const int ccol = lane & 15;
#pragma unroll
  for (int i = 0; i < 4; ++i)
#pragma unroll
    for (int j = 0; j < 4; ++j)
#pragma unroll
      for (int rr = 0; rr < 4; ++rr) {
        int row = m0 + wm * 64 + i * 16 + crow0 + rr;
        int col = n0 + wn * 64 + j * 16 + ccol;
        if (OUTBF16)
          ((unsigned short*)Cm)[(size_t)row * Ndim + col] = f2bf(acc[i][j][rr]);
        else
          ((float*)Cm)[(size_t)row * Ndim + col] = acc[i][j][rr];
      }
}

// ---------------- chunked scan (bf16 in/out, fp32 state) ----------------
__global__ void scan_phase1(const unsigned short* __restrict__ k,
                            const unsigned short* __restrict__ v,
                            const float* __restrict__ td, float* __restrict__ cs) {
  int blk = blockIdx.x;  // bh*NC + c
  int c = blk & (NC - 1);
  int bh = blk >> 5;
  int b = bh >> 4;
  int h = bh & 15;
  int s = threadIdx.x;
  float decay = expf(td[h * Sn + s]);
  size_t base = ((size_t)(b * Tn + c * LCH)) * Cn + h * Sn + s;
  float st = 0.f;
#pragma unroll 8
  for (int i = 0; i < LCH; ++i) {
    float kv = bf2f(k[base]) * bf2f(v[base]);
    st = kv + decay * st;
    base += Cn;
  }
  cs[(size_t)blk * Sn + s] = st;
}

__global__ void scan_phase2(const float* __restrict__ td, float* __restrict__ cs) {
  int bh = blockIdx.x;
  int h = bh & 15;
  int s = threadIdx.x;
  float dL = expf(td[h * Sn + s] * (float)LCH);
  float carry = 0.f;
  for (int c = 0; c < NC; ++c) {
    size_t idx = ((size_t)bh * NC + c) * Sn + s;
    float sc = cs[idx];
    cs[idx] = carry;
    carry = sc + dL * carry;
  }
}

__global__ void scan_phase3(const unsigned short* __restrict__ k,
                            const unsigned short* __restrict__ v,
                            const unsigned short* __restrict__ r,
                            const float* __restrict__ td, const float* __restrict__ tf,
                            const float* __restrict__ cs,
                            unsigned short* __restrict__ out) {
  int blk = blockIdx.x;
  int c = blk & (NC - 1);
  int bh = blk >> 5;
  int b = bh >> 4;
  int h = bh & 15;
  int s = threadIdx.x;
  float decay = expf(td[h * Sn + s]);
  float first = tf[h * Sn + s];
  float st = cs[(size_t)blk * Sn + s];
  size_t base = ((size_t)(b * Tn + c * LCH)) * Cn + h * Sn + s;
#pragma unroll 8
  for (int i = 0; i < LCH; ++i) {
    float kv = bf2f(k[base]) * bf2f(v[base]);
    st = kv + decay * st;
    out[base] = f2bf(bf2f(r[base]) * (first * kv + st));
    base += Cn;
  }
}

// ---------------- layernorm (bf16 in) -> bf16 ----------------
__global__ __launch_bounds__(256) void ln_kernel(const unsigned short* __restrict__ in,
                                                 const float* __restrict__ g,
                                                 const float* __restrict__ bb,
                                                 unsigned short* __restrict__ out) {
  int row = blockIdx.x;
  int tid = threadIdx.x;
  size_t base = (size_t)row * Cn + tid * 4;
  ushort4 uv = *(const ushort4*)(in + base);
  float4 xv = {bf2f(uv.x), bf2f(uv.y), bf2f(uv.z), bf2f(uv.w)};
  float sum = xv.x + xv.y + xv.z + xv.w;
  float ss = xv.x * xv.x + xv.y * xv.y + xv.z * xv.z + xv.w * xv.w;
#pragma unroll
  for (int off = 32; off >= 1; off >>= 1) {
    sum += __shfl_down(sum, off, 64);
    ss += __shfl_down(ss, off, 64);
  }
  __shared__ float s1[4], s2[4];
  if ((tid & 63) == 0) { s1[tid >> 6] = sum; s2[tid >> 6] = ss; }
  __syncthreads();
  sum = s1[0] + s1[1] + s1[2] + s1[3];
  ss = s2[0] + s2[1] + s2[2] + s2[3];
  float mu = sum * (1.f / Cn);
  float var = ss * (1.f / Cn) - mu * mu;
  float rstd = rsqrtf(var + 1e-5f);
  float4 gv = *(const float4*)(g + tid * 4);
  float4 bv = *(const float4*)(bb + tid * 4);
  ushort4 o;
  o.x = f2bf((xv.x - mu) * rstd * gv.x + bv.x);
  o.y = f2bf((xv.y - mu) * rstd * gv.y + bv.y);
  o.z = f2bf((xv.z - mu) * rstd * gv.z + bv.z);
  o.w = f2bf((xv.w - mu) * rstd * gv.w + bv.w);
  *(ushort4*)(out + base) = o;
}

extern "C" void kernel_launch(void* const* d_in, const int* in_sizes, int n_in,
                              void* d_out, int out_size, void* d_ws, size_t ws_size,
                              hipStream_t stream) {
  const float* x   = (const float*)d_in[0];
  const float* tmk = (const float*)d_in[1];
  const float* tmv = (const float*)d_in[2];
  const float* tmr = (const float*)d_in[3];
  const float* td  = (const float*)d_in[4];
  const float* tf  = (const float*)d_in[5];
  const float* Wk  = (const float*)d_in[6];
  const float* Wv  = (const float*)d_in[7];
  const float* Wr  = (const float*)d_in[8];
  const float* Wo  = (const float*)d_in[9];
  const float* lng = (const float*)d_in[10];
  const float* lnb = (const float*)d_in[11];
  float* out = (float*)d_out;

  char* ws = (char*)d_ws;
  const size_t MB = 1024 * 1024;
  unsigned short* wbf  = (unsigned short*)(ws);              // 8 MB (4 weights bf16)
  unsigned short* xk   = (unsigned short*)(ws + 8 * MB);     // 32 MB
  unsigned short* xv_  = (unsigned short*)(ws + 40 * MB);    // 32 MB
  unsigned short* xr   = (unsigned short*)(ws + 72 * MB);    // 32 MB
  unsigned short* bufK = (unsigned short*)(ws + 104 * MB);   // 32 MB
  unsigned short* bufV = (unsigned short*)(ws + 136 * MB);   // 32 MB
  unsigned short* bufR = (unsigned short*)(ws + 168 * MB);   // 32 MB
  unsigned short* preLN = xk;                                // reuse (xk consumed by GEMM)
  unsigned short* lnout = xv_;                               // reuse
  float* chunkS = (float*)(ws + 200 * MB);                   // 1 MB

  const int gemm_grid = (Mn / BM) * (Cn / BN);  // 1024
  const int mix_grid = Mn * (Cn / 4) / 256;     // 16384

  wconv_kernel<<<4 * Cn * Cn / 4 / 256, 256, 0, stream>>>(Wk, Wv, Wr, Wo, wbf);
  mix3_kernel<<<mix_grid, 256, 0, stream>>>(x, tmk, tmv, tmr, xk, xv_, xr);

  gemm_bt<true><<<gemm_grid, 256, 0, stream>>>(xk,  wbf + 0 * (size_t)Cn * Cn, bufK, Mn, Cn, Cn);
  gemm_bt<true><<<gemm_grid, 256, 0, stream>>>(xv_, wbf + 1 * (size_t)Cn * Cn, bufV, Mn, Cn, Cn);
  gemm_bt<true><<<gemm_grid, 256, 0, stream>>>(xr,  wbf + 2 * (size_t)Cn * Cn, bufR, Mn, Cn, Cn);

  scan_phase1<<<Bsz * Hn * NC, 64, 0, stream>>>(bufK, bufV, td, chunkS);
  scan_phase2<<<Bsz * Hn, 64, 0, stream>>>(td, chunkS);
  scan_phase3<<<Bsz * Hn * NC, 64, 0, stream>>>(bufK, bufV, bufR, td, tf, chunkS, preLN);

  ln_kernel<<<Mn, 256, 0, stream>>>(preLN, lng, lnb, lnout);

  gemm_bt<false><<<gemm_grid, 256, 0, stream>>>(lnout, wbf + 3 * (size_t)Cn * Cn, out, Mn, Cn, Cn);

  (void)in_sizes; (void)n_in; (void)out_size; (void)ws_size;
}

// Round 3
// 247.716 us; speedup vs baseline: 1.7774x; 1.3437x over previous
//
#include <hip/hip_runtime.h>

#define Bsz 8
#define Tn  2048
#define Cn  1024
#define Hn  16
#define Sn  64
#define Mn  (Bsz * Tn)   // 16384
#define NC  32
#define LCH (Tn / NC)    // 64
#define Kd  1024
#define NKT (Kd / 64)    // 16 K-tiles of 64

typedef __attribute__((ext_vector_type(8))) short bf16x8;
typedef __attribute__((ext_vector_type(4))) float f32x4;

__device__ __forceinline__ unsigned short f2bf(float f) {
  union { float f; unsigned int u; } v;
  v.f = f;
  unsigned int r = (v.u + 0x7FFFu + ((v.u >> 16) & 1u)) >> 16;
  return (unsigned short)r;
}
__device__ __forceinline__ float bf2f(unsigned short u) {
  union { unsigned int u; float f; } v;
  v.u = ((unsigned int)u) << 16;
  return v.f;
}

// ---------------- weight fp32 -> bf16 ----------------
__global__ void wconv_kernel(const float* __restrict__ Wk, const float* __restrict__ Wv,
                             const float* __restrict__ Wr, const float* __restrict__ Wo,
                             unsigned short* __restrict__ out) {
  int i = blockIdx.x * blockDim.x + threadIdx.x;
  int which = i >> 18;
  int off = (i & 0x3FFFF) * 4;
  const float* src = which == 0 ? Wk : which == 1 ? Wv : which == 2 ? Wr : Wo;
  float4 f = *(const float4*)(src + off);
  ushort4 o;
  o.x = f2bf(f.x); o.y = f2bf(f.y); o.z = f2bf(f.z); o.w = f2bf(f.w);
  *(ushort4*)(out + (size_t)which * (Cn * Cn) + off) = o;
}

// ---------------- fused time-shift mix ----------------
__global__ void mix3_kernel(const float* __restrict__ x,
                            const float* __restrict__ tmk, const float* __restrict__ tmv,
                            const float* __restrict__ tmr,
                            unsigned short* __restrict__ ok, unsigned short* __restrict__ ov,
                            unsigned short* __restrict__ orr) {
  int idx = blockIdx.x * blockDim.x + threadIdx.x;
  int c4 = idx & (Cn / 4 - 1);
  int bt = idx >> 8;
  int t = bt & (Tn - 1);
  size_t base = (size_t)bt * Cn + c4 * 4;
  float4 xv = *(const float4*)(x + base);
  float4 xxv = {0.f, 0.f, 0.f, 0.f};
  if (t != 0) xxv = *(const float4*)(x + base - Cn);
  float4 dx = {xv.x - xxv.x, xv.y - xxv.y, xv.z - xxv.z, xv.w - xxv.w};
  float4 tk = *(const float4*)(tmk + c4 * 4);
  float4 tv = *(const float4*)(tmv + c4 * 4);
  float4 tr = *(const float4*)(tmr + c4 * 4);
  ushort4 a, b, c;
  a.x = f2bf(xxv.x + tk.x * dx.x); a.y = f2bf(xxv.y + tk.y * dx.y);
  a.z = f2bf(xxv.z + tk.z * dx.z); a.w = f2bf(xxv.w + tk.w * dx.w);
  b.x = f2bf(xxv.x + tv.x * dx.x); b.y = f2bf(xxv.y + tv.y * dx.y);
  b.z = f2bf(xxv.z + tv.z * dx.z); b.w = f2bf(xxv.w + tv.w * dx.w);
  c.x = f2bf(xxv.x + tr.x * dx.x); c.y = f2bf(xxv.y + tr.y * dx.y);
  c.z = f2bf(xxv.z + tr.z * dx.z); c.w = f2bf(xxv.w + tr.w * dx.w);
  *(ushort4*)(ok + base) = a;
  *(ushort4*)(ov + base) = b;
  *(ushort4*)(orr + base) = c;
}

// ---------------- 256x256-tile GEMM, counted-vmcnt pipeline ----------------
// C[m,n] = sum_k A[m,k] * Bt[n,k]; M=16384, N=K=1024 fixed.
__device__ __forceinline__ void gload_lds16(const void* g, void* l) {
  __builtin_amdgcn_global_load_lds((const __attribute__((address_space(1))) void*)g,
                                   (__attribute__((address_space(3))) void*)l, 16, 0, 0);
}

template <bool OUTBF16>
__global__ __launch_bounds__(512, 2) void gemm256(const unsigned short* __restrict__ A,
                                                  const unsigned short* __restrict__ Bt,
                                                  void* __restrict__ Cm) {
  // LDS: 2 buffers x { A-kh0 16K | A-kh1 16K | B-kh0 16K | B-kh1 16K } = 128 KB
  // Unit = 256 rows x 32 cols bf16, row = 64B, chunk XOR-swizzle cc ^= (row>>1)&3.
  __shared__ unsigned short lds[65536];
  char* ldsc = (char*)lds;
  const int tid = threadIdx.x;
  const int wid = tid >> 6, lane = tid & 63;
  const int wm = wid >> 2, wn = wid & 3;
  int bid = ((int)blockIdx.x & 7) * 32 + ((int)blockIdx.x >> 3);  // XCD-bijective
  const int mt = bid >> 2, nt = bid & 3;
  const int m0 = mt * 256, n0 = nt * 256;

  const unsigned short* Ag = A + (size_t)m0 * Kd;
  const unsigned short* Bg = Bt + (size_t)n0 * Kd;

  // stage one 256x32 unit: 2 gload_lds16 per thread; LDS linear, source pre-swizzled
  auto stage = [&](const unsigned short* gbase, int gcol0, int ldsoff) {
#pragma unroll
    for (int j = 0; j < 2; ++j) {
      int c = tid + j * 512;
      int row = c >> 2, cc = c & 3;
      const unsigned short* g = gbase + (size_t)row * Kd + gcol0 + ((cc ^ ((row >> 1) & 3)) << 3);
      gload_lds16(g, ldsc + ldsoff + (wid * 64 + j * 512) * 16);
    }
  };

  const int l15 = lane & 15, lg = lane >> 4;
  const int axr = (lg ^ ((l15 >> 1) & 3)) << 4;   // per-lane swizzled chunk offset
  const int arow = (wm * 128 + l15) * 64;          // + mi*1024
  const int brow = (wn * 64 + l15) * 64;           // + nj*1024

  f32x4 acc[8][4] = {};

  // prologue: K-tile 0 into buf0, batch order {AK0,BK0},{AK1,BK1}
  stage(Ag, 0, 0);
  stage(Bg, 0, 32768);
  asm volatile("" ::: "memory");   // pin batch boundary
  stage(Ag, 32, 16384);
  stage(Bg, 32, 49152);

#pragma unroll 2
  for (int kt = 0; kt < NKT; ++kt) {
    const int bbase = (kt & 1) << 16;
    const int nbase = bbase ^ 65536;
    const int k1 = (kt + 1) * 64;
    const bool st = (kt < NKT - 1);

    // ---------- sub-phase 0 (ks = 0) ----------
    if (st) { stage(Ag, k1, nbase); stage(Bg, k1, nbase + 32768); }
    if (st) asm volatile("s_waitcnt vmcnt(8)" ::: "memory");
    else    asm volatile("s_waitcnt vmcnt(4)" ::: "memory");
    __builtin_amdgcn_s_barrier();
    __builtin_amdgcn_sched_barrier(0);
    {
      bf16x8 bfr[4], afr[8];
#pragma unroll
      for (int nj = 0; nj < 4; ++nj)
        bfr[nj] = *(const bf16x8*)(ldsc + bbase + 32768 + brow + nj * 1024 + axr);
#pragma unroll
      for (int mi = 0; mi < 8; ++mi)
        afr[mi] = *(const bf16x8*)(ldsc + bbase + arow + mi * 1024 + axr);
      __builtin_amdgcn_s_setprio(1);
#pragma unroll
      for (int mi = 0; mi < 8; ++mi)
#pragma unroll
        for (int nj = 0; nj < 4; ++nj)
          acc[mi][nj] = __builtin_amdgcn_mfma_f32_16x16x32_bf16(afr[mi], bfr[nj], acc[mi][nj], 0, 0, 0);
      __builtin_amdgcn_s_setprio(0);
    }

    // ---------- sub-phase 1 (ks = 1) ----------
    if (st) { stage(Ag, k1 + 32, nbase + 16384); stage(Bg, k1 + 32, nbase + 49152); }
    if (st) asm volatile("s_waitcnt vmcnt(8)" ::: "memory");
    else    asm volatile("s_waitcnt vmcnt(0)" ::: "memory");
    __builtin_amdgcn_s_barrier();
    __builtin_amdgcn_sched_barrier(0);
    {
      bf16x8 bfr[4], afr[8];
#pragma unroll
      for (int nj = 0; nj < 4; ++nj)
        bfr[nj] = *(const bf16x8*)(ldsc + bbase + 49152 + brow + nj * 1024 + axr);
#pragma unroll
      for (int mi = 0; mi < 8; ++mi)
        afr[mi] = *(const bf16x8*)(ldsc + bbase + 16384 + arow + mi * 1024 + axr);
      __builtin_amdgcn_s_setprio(1);
#pragma unroll
      for (int mi = 0; mi < 8; ++mi)
#pragma unroll
        for (int nj = 0; nj < 4; ++nj)
          acc[mi][nj] = __builtin_amdgcn_mfma_f32_16x16x32_bf16(afr[mi], bfr[nj], acc[mi][nj], 0, 0, 0);
      __builtin_amdgcn_s_setprio(0);
    }
  }

  // epilogue: C/D layout col=lane&15, row=(lane>>4)*4+rr (verified convention)
#pragma unroll
  for (int mi = 0; mi < 8; ++mi)
#pragma unroll
    for (int nj = 0; nj < 4; ++nj)
#pragma unroll
      for (int rr = 0; rr < 4; ++rr) {
        int row = m0 + wm * 128 + mi * 16 + (lane >> 4) * 4 + rr;
        int col = n0 + wn * 64 + nj * 16 + (lane & 15);
        if (OUTBF16)
          ((unsigned short*)Cm)[(size_t)row * Cn + col] = f2bf(acc[mi][nj][rr]);
        else
          ((float*)Cm)[(size_t)row * Cn + col] = acc[mi][nj][rr];
      }
}

// ---------------- chunked scan (bf16 in/out, fp32 state) ----------------
__global__ void scan_phase1(const unsigned short* __restrict__ k,
                            const unsigned short* __restrict__ v,
                            const float* __restrict__ td, float* __restrict__ cs) {
  int blk = blockIdx.x;
  int c = blk & (NC - 1);
  int bh = blk >> 5;
  int b = bh >> 4;
  int h = bh & 15;
  int s = threadIdx.x;
  float decay = expf(td[h * Sn + s]);
  size_t base = ((size_t)(b * Tn + c * LCH)) * Cn + h * Sn + s;
  float st = 0.f;
#pragma unroll 8
  for (int i = 0; i < LCH; ++i) {
    float kv = bf2f(k[base]) * bf2f(v[base]);
    st = kv + decay * st;
    base += Cn;
  }
  cs[(size_t)blk * Sn + s] = st;
}

__global__ void scan_phase2(const float* __restrict__ td, float* __restrict__ cs) {
  int bh = blockIdx.x;
  int h = bh & 15;
  int s = threadIdx.x;
  float dL = expf(td[h * Sn + s] * (float)LCH);
  float carry = 0.f;
  for (int c = 0; c < NC; ++c) {
    size_t idx = ((size_t)bh * NC + c) * Sn + s;
    float sc = cs[idx];
    cs[idx] = carry;
    carry = sc + dL * carry;
  }
}

__global__ void scan_phase3(const unsigned short* __restrict__ k,
                            const unsigned short* __restrict__ v,
                            const unsigned short* __restrict__ r,
                            const float* __restrict__ td, const float* __restrict__ tf,
                            const float* __restrict__ cs,
                            unsigned short* __restrict__ out) {
  int blk = blockIdx.x;
  int c = blk & (NC - 1);
  int bh = blk >> 5;
  int b = bh >> 4;
  int h = bh & 15;
  int s = threadIdx.x;
  float decay = expf(td[h * Sn + s]);
  float first = tf[h * Sn + s];
  float st = cs[(size_t)blk * Sn + s];
  size_t base = ((size_t)(b * Tn + c * LCH)) * Cn + h * Sn + s;
#pragma unroll 8
  for (int i = 0; i < LCH; ++i) {
    float kv = bf2f(k[base]) * bf2f(v[base]);
    st = kv + decay * st;
    out[base] = f2bf(bf2f(r[base]) * (first * kv + st));
    base += Cn;
  }
}

// ---------------- layernorm (bf16 in) -> bf16 ----------------
__global__ __launch_bounds__(256) void ln_kernel(const unsigned short* __restrict__ in,
                                                 const float* __restrict__ g,
                                                 const float* __restrict__ bb,
                                                 unsigned short* __restrict__ out) {
  int row = blockIdx.x;
  int tid = threadIdx.x;
  size_t base = (size_t)row * Cn + tid * 4;
  ushort4 uv = *(const ushort4*)(in + base);
  float4 xv = {bf2f(uv.x), bf2f(uv.y), bf2f(uv.z), bf2f(uv.w)};
  float sum = xv.x + xv.y + xv.z + xv.w;
  float ss = xv.x * xv.x + xv.y * xv.y + xv.z * xv.z + xv.w * xv.w;
#pragma unroll
  for (int off = 32; off >= 1; off >>= 1) {
    sum += __shfl_down(sum, off, 64);
    ss += __shfl_down(ss, off, 64);
  }
  __shared__ float s1[4], s2[4];
  if ((tid & 63) == 0) { s1[tid >> 6] = sum; s2[tid >> 6] = ss; }
  __syncthreads();
  sum = s1[0] + s1[1] + s1[2] + s1[3];
  ss = s2[0] + s2[1] + s2[2] + s2[3];
  float mu = sum * (1.f / Cn);
  float var = ss * (1.f / Cn) - mu * mu;
  float rstd = rsqrtf(var + 1e-5f);
  float4 gv = *(const float4*)(g + tid * 4);
  float4 bv = *(const float4*)(bb + tid * 4);
  ushort4 o;
  o.x = f2bf((xv.x - mu) * rstd * gv.x + bv.x);
  o.y = f2bf((xv.y - mu) * rstd * gv.y + bv.y);
  o.z = f2bf((xv.z - mu) * rstd * gv.z + bv.z);
  o.w = f2bf((xv.w - mu) * rstd * gv.w + bv.w);
  *(ushort4*)(out + base) = o;
}

extern "C" void kernel_launch(void* const* d_in, const int* in_sizes, int n_in,
                              void* d_out, int out_size, void* d_ws, size_t ws_size,
                              hipStream_t stream) {
  const float* x   = (const float*)d_in[0];
  const float* tmk = (const float*)d_in[1];
  const float* tmv = (const float*)d_in[2];
  const float* tmr = (const float*)d_in[3];
  const float* td  = (const float*)d_in[4];
  const float* tf  = (const float*)d_in[5];
  const float* Wk  = (const float*)d_in[6];
  const float* Wv  = (const float*)d_in[7];
  const float* Wr  = (const float*)d_in[8];
  const float* Wo  = (const float*)d_in[9];
  const float* lng = (const float*)d_in[10];
  const float* lnb = (const float*)d_in[11];
  float* out = (float*)d_out;

  char* ws = (char*)d_ws;
  const size_t MB = 1024 * 1024;
  unsigned short* wbf  = (unsigned short*)(ws);              // 8 MB (4 weights bf16)
  unsigned short* xk   = (unsigned short*)(ws + 8 * MB);     // 32 MB
  unsigned short* xv_  = (unsigned short*)(ws + 40 * MB);    // 32 MB
  unsigned short* xr   = (unsigned short*)(ws + 72 * MB);    // 32 MB
  unsigned short* bufK = (unsigned short*)(ws + 104 * MB);   // 32 MB
  unsigned short* bufV = (unsigned short*)(ws + 136 * MB);   // 32 MB
  unsigned short* bufR = (unsigned short*)(ws + 168 * MB);   // 32 MB
  unsigned short* preLN = xk;                                // reuse
  unsigned short* lnout = xv_;                               // reuse
  float* chunkS = (float*)(ws + 200 * MB);                   // 1 MB

  const int gemm_grid = (Mn / 256) * (Cn / 256);  // 64 * 4 = 256
  const int mix_grid = Mn * (Cn / 4) / 256;       // 16384

  wconv_kernel<<<4 * Cn * Cn / 4 / 256, 256, 0, stream>>>(Wk, Wv, Wr, Wo, wbf);
  mix3_kernel<<<mix_grid, 256, 0, stream>>>(x, tmk, tmv, tmr, xk, xv_, xr);

  gemm256<true><<<gemm_grid, 512, 0, stream>>>(xk,  wbf + 0 * (size_t)Cn * Cn, bufK);
  gemm256<true><<<gemm_grid, 512, 0, stream>>>(xv_, wbf + 1 * (size_t)Cn * Cn, bufV);
  gemm256<true><<<gemm_grid, 512, 0, stream>>>(xr,  wbf + 2 * (size_t)Cn * Cn, bufR);

  scan_phase1<<<Bsz * Hn * NC, 64, 0, stream>>>(bufK, bufV, td, chunkS);
  scan_phase2<<<Bsz * Hn, 64, 0, stream>>>(td, chunkS);
  scan_phase3<<<Bsz * Hn * NC, 64, 0, stream>>>(bufK, bufV, bufR, td, tf, chunkS, preLN);

  ln_kernel<<<Mn, 256, 0, stream>>>(preLN, lng, lnb, lnout);

  gemm256<false><<<gemm_grid, 512, 0, stream>>>(lnout, wbf + 3 * (size_t)Cn * Cn, out);

  (void)in_sizes; (void)n_in; (void)out_size; (void)ws_size;
}